// Round 9
// baseline (645.159 us; speedup 1.0000x reference)
//
#include <hip/hip_runtime.h>
#include <hip/hip_bf16.h>
#include <stdint.h>

// Problem constants
#define MTOK 16384   // B*S
#define HID  2048
#define NQKV 6144    // 3*HID
#define GK   2048    // K of both GEMMs
#define NKT  (GK / 64)    // 32 K-tiles
#define NREG (NKT * 4)    // 128 staging regions (A_k0,B_k0,A_k1,B_k1 per tile)
#define SLOT 16384        // bytes per LDS region slot
#define RING (9 * SLOT)   // 147456 B: 9-slot ring

typedef __attribute__((ext_vector_type(8))) short bf16x8;
typedef __attribute__((ext_vector_type(4))) float f32x4;

__device__ __forceinline__ unsigned short f2bf(float f) {
  uint32_t u = __float_as_uint(f);
  u = (u + 0x7FFFu + ((u >> 16) & 1u)) >> 16;   // round-to-nearest-even
  return (unsigned short)u;
}
__device__ __forceinline__ void bf2x2(uint32_t u, float& lo, float& hi) {
  lo = __uint_as_float(u << 16);
  hi = __uint_as_float(u & 0xFFFF0000u);
}

__device__ __forceinline__ void gld_lds16(const void* g, void* l) {
  __builtin_amdgcn_global_load_lds(
      (const __attribute__((address_space(1))) uint32_t*)g,
      (__attribute__((address_space(3))) uint32_t*)l, 16, 0, 0);
}

// ---------------- fp32 -> bf16 elementwise convert (8 elems/thread/iter) ---
__global__ void convert_f32_bf16(const float* __restrict__ in,
                                 unsigned short* __restrict__ out, int n8) {
  int idx = blockIdx.x * blockDim.x + threadIdx.x;
  int stride = gridDim.x * blockDim.x;
  for (int i = idx; i < n8; i += stride) {
    const float4* p = (const float4*)(in + (size_t)i * 8);
    float4 a = p[0], b = p[1];
    union { bf16x8 v; unsigned short u[8]; } o;
    o.u[0] = f2bf(a.x); o.u[1] = f2bf(a.y); o.u[2] = f2bf(a.z); o.u[3] = f2bf(a.w);
    o.u[4] = f2bf(b.x); o.u[5] = f2bf(b.y); o.u[6] = f2bf(b.z); o.u[7] = f2bf(b.w);
    *(bf16x8*)(out + (size_t)i * 8) = o.v;
  }
}

// ------- 4x W[K][N] f32 -> Wt[N][K] bf16 (64x64 LDS tiles), z picks W ------
__global__ void transpose4_to_bf16(const float* __restrict__ Wq,
                                   const float* __restrict__ Wk,
                                   const float* __restrict__ Wv,
                                   const float* __restrict__ Wo,
                                   unsigned short* __restrict__ Wqkvt,
                                   unsigned short* __restrict__ Wot) {
  __shared__ float tile[64][65];
  const float* W;
  unsigned short* Wt;
  const int z = blockIdx.z;
  if (z == 0)      { W = Wq; Wt = Wqkvt; }
  else if (z == 1) { W = Wk; Wt = Wqkvt + (size_t)HID * HID; }
  else if (z == 2) { W = Wv; Wt = Wqkvt + (size_t)2 * HID * HID; }
  else             { W = Wo; Wt = Wot; }
  int tk = blockIdx.x * 64, tn = blockIdx.y * 64;
  int t = threadIdx.x;
  int c = t & 63, rb = t >> 6;
#pragma unroll
  for (int i = 0; i < 16; i++) {
    int r = i * 4 + rb;
    tile[r][c] = W[(size_t)(tk + r) * HID + tn + c];
  }
  __syncthreads();
#pragma unroll
  for (int i = 0; i < 16; i++) {
    int r = i * 4 + rb;  // r = n index, c = k index
    Wt[(size_t)(tn + r) * HID + tk + c] = f2bf(tile[c][r]);
  }
}

// ---------------- bias concat [bq|bk|bv] -> [6144] f32 ---------------------
__global__ void concat_bias(const float* __restrict__ bq,
                            const float* __restrict__ bk,
                            const float* __restrict__ bv,
                            float* __restrict__ out) {
  int i = blockIdx.x * blockDim.x + threadIdx.x;
  if (i < 2048)       out[i] = bq[i];
  else if (i < 4096)  out[i] = bk[i - 2048];
  else if (i < 6144)  out[i] = bv[i - 4096];
}

// ===========================================================================
// 256x256 bf16 GEMM — r9: ONE barrier per K-tile, dataflow-gated WAR.
//
// 9-slot ring (16 KiB regions), region S_J slot = J mod 9. Swizzle
// involution byte ^= ((row>>1)&3)<<4 on ds_read, inverse pre-applied to
// global source (rule #21). XCD banding as r5.
//
// Tile u stages {S_{4u+5}..S_{4u+8}} at TOP -> overwrites slots of
// {S_{4u-4}..S_{4u-1}} = tile u-1's regions. WAR proof: every ds_read of a
// tile's 4 regions is consumed by a P-group MFMA before that tile's close
// barrier (waitcnt pass enforces read-complete before MFMA issue), so by
// barrier arrival all waves' reads are complete; stages issue only after.
// No mid-barrier, no lgkmcnt asm needed.
//
// RAW: close = vmcnt(2) + s_barrier. Ledger: at close of tile u, outstanding
// = 2 (prev) + 8 (top) = 10 -> drain to 2 completes through S_{4u+7};
// tile u+1 reads S_{4u+4..4u+7} all landed. Prologue: stage S0..S4
// (10 loads), vmcnt(2) -> S0..S3 landed, barrier.
//
// Body interleave (sched_barrier(0)-pinned): R0(A0h0+B0) R1(A0h1+B1)
// P0(aAxb0) R2(A1h0) P1(aBxb0) R3(A1h1) P2(aCxb1) P3(aDxb1) -> ~16 of 24
// ds_reads stream under MFMA issue.
// ===========================================================================
template <bool F32OUT>
__global__ __launch_bounds__(512, 2) void gemm256(
    const unsigned short* __restrict__ A,   // [M][GK] bf16
    const unsigned short* __restrict__ Bt,  // [N][GK] bf16
    const float* __restrict__ bias,         // [N]
    unsigned short* __restrict__ Cb, float* __restrict__ Cf,
    int M, int N) {
  extern __shared__ __align__(16) char lds[];

  // ---- locality-aware XCD banding (ntm == 64 assumed) ----
  const int bid = blockIdx.x;
  const int xcd = bid & 7;
  const int i6 = bid >> 3;              // [0, nwg/8)
  const int tm = xcd * 8 + (i6 & 7);    // exclusive 8-row A-band per XCD
  const int tn = i6 >> 3;               // tn walked in lockstep across XCDs

  const int tid = threadIdx.x;
  const int wave = tid >> 6, lane = tid & 63;
  const int wr = wave >> 2, wc = wave & 3;   // 2M x 4N waves, 128x64 out each

  // ---- staging addressing (per-thread, bytes) ----
  const int colb = ((tid & 3) << 4) ^ (((tid >> 3) & 3) << 4);
  const size_t g0 = (size_t)(tid >> 2) * (GK * 2) + colb;
  const size_t g1 = g0 + (size_t)128 * (GK * 2);
  const char* Ab = (const char*)A + (size_t)tm * 256 * (GK * 2);
  const char* Bb = (const char*)Bt + (size_t)tn * 256 * (GK * 2);

#define STAGE(J, DST)                                                     \
  do {                                                                    \
    if ((J) < NREG) {                                                     \
      const int _t = (J) >> 2;                                            \
      const char* _s = (((J)&1) ? Bb : Ab) + (size_t)(_t)*128 +           \
                       ((((J) >> 1) & 1) * 64);                           \
      char* _d = lds + (DST) + (wave << 10);                              \
      gld_lds16(_s + g0, _d);                                             \
      gld_lds16(_s + g1, _d + 8192);                                      \
    }                                                                     \
  } while (0)

  // ---- fragment read addressing ----
  const int fr = lane & 15;
  const int fkb = (lane >> 4) << 4;                           // k-offset bytes
  const int lofs = fr * 64 + (fkb ^ (((fr >> 1) & 3) << 4));  // swizzled

  f32x4 acc[8][4];
#pragma unroll
  for (int m = 0; m < 8; m++)
#pragma unroll
    for (int n = 0; n < 4; n++) acc[m][n] = (f32x4){0.f, 0.f, 0.f, 0.f};
  bf16x8 aA[4], aB[4], aC[4], aD[4], b0[4], b1[4];

  // ---- ring cursors: rs[i]=slot(S_{4u+i}); wsl[j]=slot(S_{4u+5+j}) ----
  int rs[4] = {0, SLOT, 2 * SLOT, 3 * SLOT};
  int wsl[4] = {5 * SLOT, 6 * SLOT, 7 * SLOT, 8 * SLOT};

  // ---- prologue: stage S_0..S_4 into slots 0..4 ----
  STAGE(0, 0); STAGE(1, SLOT); STAGE(2, 2 * SLOT); STAGE(3, 3 * SLOT);
  STAGE(4, 4 * SLOT);
  asm volatile("s_waitcnt vmcnt(2)" ::: "memory");  // S_0..S_3 landed
  __builtin_amdgcn_s_barrier();

  for (int u = 0; u < NKT; ++u) {
    // ---- top: stage 4 regions (overwrite tile u-1's read-complete slots)
    STAGE(u * 4 + 5, wsl[0]);
    STAGE(u * 4 + 6, wsl[1]);
    STAGE(u * 4 + 7, wsl[2]);
    STAGE(u * 4 + 8, wsl[3]);

    const char* a0p = lds + rs[0] + wr * 8192 + lofs;
    const char* b0p = lds + rs[1] + wc * 4096 + lofs;
    const char* a1p = lds + rs[2] + wr * 8192 + lofs;
    const char* b1p = lds + rs[3] + wc * 4096 + lofs;

    // R0: A0h0 + B0
#pragma unroll
    for (int m = 0; m < 4; m++) aA[m] = *(const bf16x8*)(a0p + m * 1024);
#pragma unroll
    for (int n = 0; n < 4; n++) b0[n] = *(const bf16x8*)(b0p + n * 1024);
    __builtin_amdgcn_sched_barrier(0);
    // R1: A0h1 + B1
#pragma unroll
    for (int m = 0; m < 4; m++) aB[m] = *(const bf16x8*)(a0p + 4096 + m * 1024);
#pragma unroll
    for (int n = 0; n < 4; n++) b1[n] = *(const bf16x8*)(b1p + n * 1024);
    __builtin_amdgcn_sched_barrier(0);

    // P0: needs R0; R1 streams underneath
    __builtin_amdgcn_s_setprio(1);
#pragma unroll
    for (int m = 0; m < 4; m++)
#pragma unroll
      for (int n = 0; n < 4; n++)
        acc[m][n] = __builtin_amdgcn_mfma_f32_16x16x32_bf16(aA[m], b0[n],
                                                            acc[m][n], 0, 0, 0);
    __builtin_amdgcn_s_setprio(0);
    __builtin_amdgcn_sched_barrier(0);

    // R2: A1h0
#pragma unroll
    for (int m = 0; m < 4; m++) aC[m] = *(const bf16x8*)(a1p + m * 1024);
    __builtin_amdgcn_sched_barrier(0);

    // P1: needs R1; R2 streams underneath
    __builtin_amdgcn_s_setprio(1);
#pragma unroll
    for (int m = 0; m < 4; m++)
#pragma unroll
      for (int n = 0; n < 4; n++)
        acc[4 + m][n] = __builtin_amdgcn_mfma_f32_16x16x32_bf16(
            aB[m], b0[n], acc[4 + m][n], 0, 0, 0);
    __builtin_amdgcn_s_setprio(0);
    __builtin_amdgcn_sched_barrier(0);

    // R3: A1h1
#pragma unroll
    for (int m = 0; m < 4; m++) aD[m] = *(const bf16x8*)(a1p + 4096 + m * 1024);
    __builtin_amdgcn_sched_barrier(0);

    // P2: needs R2; R3 streams underneath
    __builtin_amdgcn_s_setprio(1);
#pragma unroll
    for (int m = 0; m < 4; m++)
#pragma unroll
      for (int n = 0; n < 4; n++)
        acc[m][n] = __builtin_amdgcn_mfma_f32_16x16x32_bf16(aC[m], b1[n],
                                                            acc[m][n], 0, 0, 0);
    __builtin_amdgcn_s_setprio(0);
    __builtin_amdgcn_sched_barrier(0);

    // P3: needs R3
    __builtin_amdgcn_s_setprio(1);
#pragma unroll
    for (int m = 0; m < 4; m++)
#pragma unroll
      for (int n = 0; n < 4; n++)
        acc[4 + m][n] = __builtin_amdgcn_mfma_f32_16x16x32_bf16(
            aD[m], b1[n], acc[4 + m][n], 0, 0, 0);
    __builtin_amdgcn_s_setprio(0);

    // ---- close: all 24 reads consumed above; counted vmcnt then barrier
    asm volatile("s_waitcnt vmcnt(2)" ::: "memory");
    __builtin_amdgcn_s_barrier();

#pragma unroll
    for (int i = 0; i < 4; i++) {
      rs[i] += 4 * SLOT;  if (rs[i] >= RING)  rs[i] -= RING;
      wsl[i] += 4 * SLOT; if (wsl[i] >= RING) wsl[i] -= RING;
    }
  }
#undef STAGE

  // ---- epilogue: C/D layout col=lane&15, row=(lane>>4)*4+reg ----
  const int fq = lane >> 4;
#pragma unroll
  for (int mp = 0; mp < 8; mp++) {
#pragma unroll
    for (int n = 0; n < 4; n++) {
      const int col = tn * 256 + wc * 64 + n * 16 + fr;
      const float bb = bias[col];
#pragma unroll
      for (int r = 0; r < 4; r++) {
        const int row = tm * 256 + wr * 128 + mp * 16 + fq * 4 + r;
        const float v = acc[mp][n][r] + bb;
        if constexpr (F32OUT) Cf[(size_t)row * N + col] = v;
        else                  Cb[(size_t)row * N + col] = f2bf(v);
      }
    }
  }
}

// ===========================================================================
// MFMA per-token head-attention (v4, passing r7). 1 wave/token, NO LDS.
// ===========================================================================
__global__ __launch_bounds__(256) void attn_mfma(
    const unsigned short* __restrict__ qkv,  // [MTOK][6144] bf16
    unsigned short* __restrict__ attn,       // [MTOK][2048] bf16
    const float* __restrict__ c_scale) {
  const int wave = threadIdx.x >> 6, lane = threadIdx.x & 63;
  const int tok = blockIdx.x * 4 + wave;
  const unsigned short* src = qkv + (size_t)tok * NQKV;
  const int fr = lane & 15;
  const int hi = lane >> 4;

  // ---- Q,K fragments straight from global (identical addressing) ----
  const int fk = hi * 8;
  bf16x8 qf[4], kf[4];
#pragma unroll
  for (int kc = 0; kc < 4; kc++) {
    qf[kc] = *(const bf16x8*)(src + fr * 128 + kc * 32 + fk);
    kf[kc] = *(const bf16x8*)(src + HID + fr * 128 + kc * 32 + fk);
  }

  // ---- S^T = K . Q^T : lane holds S[g=hi*4+r][h=fr] ----
  f32x4 s = (f32x4){0.f, 0.f, 0.f, 0.f};
#pragma unroll
  for (int kc = 0; kc < 4; kc++)
    s = __builtin_amdgcn_mfma_f32_16x16x32_bf16(kf[kc], qf[kc], s, 0, 0, 0);

  const float scale = c_scale[0] * 0.08838834764831845f;  // 1/sqrt(128)
  float pa[4];
#pragma unroll
  for (int r = 0; r < 4; r++) pa[r] = s[r] * scale;

  // ---- softmax over g (rows): in-lane 4 + cross lane-group 16,32 ----
  float mx = fmaxf(fmaxf(pa[0], pa[1]), fmaxf(pa[2], pa[3]));
  mx = fmaxf(mx, __shfl_xor(mx, 16));
  mx = fmaxf(mx, __shfl_xor(mx, 32));
#pragma unroll
  for (int r = 0; r < 4; r++) pa[r] = __expf(pa[r] - mx);
  float sum = pa[0] + pa[1] + pa[2] + pa[3];
  sum += __shfl_xor(sum, 16);
  sum += __shfl_xor(sum, 32);
  float rsum = 1.0f / sum;
#pragma unroll
  for (int r = 0; r < 4; r++) pa[r] *= rsum;

  // ---- P A-frag: slot (hi,j) holds P[h=fr][g=hi*8+j], zero for g>=16.
  //      Source lane for P[fr][g'] is (g'>>2)*16 + fr, register g'&3. ----
  union { bf16x8 v; unsigned short u[8]; uint32_t w[4]; } pf;
  const int sidx0 = fr + (hi * 2) * 16;
#pragma unroll
  for (int j = 0; j < 8; j++) {
    float pv_ = __shfl(pa[j & 3], sidx0 + (j >> 2) * 16);
    pf.u[j] = f2bf(pv_);
  }
  if (lane >= 32) { pf.w[0] = 0; pf.w[1] = 0; pf.w[2] = 0; pf.w[3] = 0; }

  // ---- PV: V-frag slot (hi,j) = V[(hi&1)*8+j][d=dc*16+fr] via scalar
  //      global loads (same kappa_as as P for hi<2; hi>=2 x P=0 = 0). ----
  const unsigned short* vrow = src + 2 * HID + (hi & 1) * 8 * 128 + fr;
  unsigned short* dst = attn + (size_t)tok * HID;
#pragma unroll
  for (int dc = 0; dc < 8; dc++) {
    union { bf16x8 v; unsigned short u[8]; } vf;
#pragma unroll
    for (int j = 0; j < 8; j++) vf.u[j] = vrow[j * 128 + dc * 16];
    f32x4 o = __builtin_amdgcn_mfma_f32_16x16x32_bf16(
        pf.v, vf.v, (f32x4){0.f, 0.f, 0.f, 0.f}, 0, 0, 0);
#pragma unroll
    for (int r = 0; r < 4; r++)
      dst[(hi * 4 + r) * 128 + dc * 16 + fr] = f2bf(o[r]);
  }
}

// ---------------------------------------------------------------------------
extern "C" void kernel_launch(void* const* d_in, const int* in_sizes, int n_in,
                              void* d_out, int out_size, void* d_ws,
                              size_t ws_size, hipStream_t stream) {
  const float* x  = (const float*)d_in[0];
  const float* Wq = (const float*)d_in[1];
  const float* bq = (const float*)d_in[2];
  const float* Wk = (const float*)d_in[3];
  const float* bk = (const float*)d_in[4];
  const float* Wv = (const float*)d_in[5];
  const float* bv = (const float*)d_in[6];
  const float* Wo = (const float*)d_in[7];
  const float* bo = (const float*)d_in[8];
  const float* c_scale = (const float*)d_in[9];
  float* out = (float*)d_out;

  char* ws = (char*)d_ws;
  unsigned short* xb    = (unsigned short*)ws; ws += (size_t)MTOK * HID * 2;
  unsigned short* Wqkvt = (unsigned short*)ws; ws += (size_t)NQKV * HID * 2;
  unsigned short* Wot   = (unsigned short*)ws; ws += (size_t)HID * HID * 2;
  float*          biasq = (float*)ws;          ws += (size_t)NQKV * 4;
  unsigned short* qkv   = (unsigned short*)ws; ws += (size_t)MTOK * NQKV * 2;
  unsigned short* attn  = (unsigned short*)ws; ws += (size_t)MTOK * HID * 2;

  (void)hipFuncSetAttribute((const void*)&gemm256<false>,
                            hipFuncAttributeMaxDynamicSharedMemorySize, RING);
  (void)hipFuncSetAttribute((const void*)&gemm256<true>,
                            hipFuncAttributeMaxDynamicSharedMemorySize, RING);

  convert_f32_bf16<<<2048, 256, 0, stream>>>(x, xb, MTOK * HID / 8);
  transpose4_to_bf16<<<dim3(32, 32, 4), 256, 0, stream>>>(Wq, Wk, Wv, Wo,
                                                          Wqkvt, Wot);
  concat_bias<<<24, 256, 0, stream>>>(bq, bk, bv, biasq);

  // QKV projection: [16384][2048] x [6144][2048]^T -> bf16 [16384][6144]
  gemm256<false><<<(MTOK / 256) * (NQKV / 256), 512, RING, stream>>>(
      xb, Wqkvt, biasq, qkv, nullptr, MTOK, NQKV);
  attn_mfma<<<MTOK / 4, 256, 0, stream>>>(qkv, attn, c_scale);
  // O projection: [16384][2048] x [2048][2048]^T -> f32 out
  gemm256<true><<<(MTOK / 256) * (HID / 256), 512, RING, stream>>>(
      attn, Wot, bo, nullptr, out, MTOK, HID);
}

// Round 11
// 614.748 us; speedup vs baseline: 1.0495x; 1.0495x over previous
//
#include <hip/hip_runtime.h>
#include <hip/hip_bf16.h>
#include <stdint.h>

// Problem constants
#define MTOK 16384   // B*S
#define HID  2048
#define NQKV 6144    // 3*HID
#define GK   2048    // K of both GEMMs
#define NKT  (GK / 64)    // 32 K-tiles
#define NREG (NKT * 4)    // 128 staging regions (A_k0,B_k0,A_k1,B_k1 per tile)
#define SLOT 16384        // bytes per LDS region slot
#define RING (9 * SLOT)   // 147456 B: 9-slot ring

typedef __attribute__((ext_vector_type(8))) short bf16x8;
typedef __attribute__((ext_vector_type(4))) float f32x4;

__device__ __forceinline__ unsigned short f2bf(float f) {
  uint32_t u = __float_as_uint(f);
  u = (u + 0x7FFFu + ((u >> 16) & 1u)) >> 16;   // round-to-nearest-even
  return (unsigned short)u;
}
__device__ __forceinline__ void bf2x2(uint32_t u, float& lo, float& hi) {
  lo = __uint_as_float(u << 16);
  hi = __uint_as_float(u & 0xFFFF0000u);
}

__device__ __forceinline__ void gld_lds16(const void* g, void* l) {
  __builtin_amdgcn_global_load_lds(
      (const __attribute__((address_space(1))) uint32_t*)g,
      (__attribute__((address_space(3))) uint32_t*)l, 16, 0, 0);
}

// ---------------- fp32 -> bf16 elementwise convert (8 elems/thread/iter) ---
__global__ void convert_f32_bf16(const float* __restrict__ in,
                                 unsigned short* __restrict__ out, int n8) {
  int idx = blockIdx.x * blockDim.x + threadIdx.x;
  int stride = gridDim.x * blockDim.x;
  for (int i = idx; i < n8; i += stride) {
    const float4* p = (const float4*)(in + (size_t)i * 8);
    float4 a = p[0], b = p[1];
    union { bf16x8 v; unsigned short u[8]; } o;
    o.u[0] = f2bf(a.x); o.u[1] = f2bf(a.y); o.u[2] = f2bf(a.z); o.u[3] = f2bf(a.w);
    o.u[4] = f2bf(b.x); o.u[5] = f2bf(b.y); o.u[6] = f2bf(b.z); o.u[7] = f2bf(b.w);
    *(bf16x8*)(out + (size_t)i * 8) = o.v;
  }
}

// ------- 4x W[K][N] f32 -> Wt[N][K] bf16 (64x64 LDS tiles), z picks W ------
__global__ void transpose4_to_bf16(const float* __restrict__ Wq,
                                   const float* __restrict__ Wk,
                                   const float* __restrict__ Wv,
                                   const float* __restrict__ Wo,
                                   unsigned short* __restrict__ Wqkvt,
                                   unsigned short* __restrict__ Wot) {
  __shared__ float tile[64][65];
  const float* W;
  unsigned short* Wt;
  const int z = blockIdx.z;
  if (z == 0)      { W = Wq; Wt = Wqkvt; }
  else if (z == 1) { W = Wk; Wt = Wqkvt + (size_t)HID * HID; }
  else if (z == 2) { W = Wv; Wt = Wqkvt + (size_t)2 * HID * HID; }
  else             { W = Wo; Wt = Wot; }
  int tk = blockIdx.x * 64, tn = blockIdx.y * 64;
  int t = threadIdx.x;
  int c = t & 63, rb = t >> 6;
#pragma unroll
  for (int i = 0; i < 16; i++) {
    int r = i * 4 + rb;
    tile[r][c] = W[(size_t)(tk + r) * HID + tn + c];
  }
  __syncthreads();
#pragma unroll
  for (int i = 0; i < 16; i++) {
    int r = i * 4 + rb;  // r = n index, c = k index
    Wt[(size_t)(tn + r) * HID + tk + c] = f2bf(tile[c][r]);
  }
}

// ---------------- bias concat [bq|bk|bv] -> [6144] f32 ---------------------
__global__ void concat_bias(const float* __restrict__ bq,
                            const float* __restrict__ bk,
                            const float* __restrict__ bv,
                            float* __restrict__ out) {
  int i = blockIdx.x * blockDim.x + threadIdx.x;
  if (i < 2048)       out[i] = bq[i];
  else if (i < 4096)  out[i] = bk[i - 2048];
  else if (i < 6144)  out[i] = bv[i - 4096];
}

// ===========================================================================
// 256x256 bf16 GEMM, burst-read 2-barrier-per-K-tile schedule (r7 proven,
// byte-identical revert; (512,2) is the replay-validated codegen).
//
// GRID MAPPING: XCD x owns an exclusive 8-row A-band (tm = x*8 + i%8),
// walking tn = i/8 across it. A fetched from HBM once chip-wide;
// B working set L2/L3-resident.
//
// LDS: 9-slot ring of 16 KiB regions. Region S_J (J = 4u + {0:A_k0,1:B_k0,
// 2:A_k1,3:B_k1}) in slot J mod 9. Swizzle involution byte ^= ((row>>1)&3)<<4
// on ds_read addr, inverse pre-applied to global_load_lds source (rule #21).
//
// Per K-tile u (ledger-verified):
//   top:  STAGE S_{4u+7},S_{4u+8}; burst 16 ds_reads (A k0 both halves, B k0,
//         B k1); sched_barrier
//   p0/p1 MFMA (counted lgkmcnt by compiler); then 8 ds_reads A(k1)
//   mid:  lgkmcnt(12) + s_barrier; STAGE S_{4u+9},S_{4u+10}
//   p2/p3 MFMA; vmcnt(6); s_barrier (close)
// ===========================================================================
template <bool F32OUT>
__global__ __launch_bounds__(512, 2) void gemm256(
    const unsigned short* __restrict__ A,   // [M][GK] bf16
    const unsigned short* __restrict__ Bt,  // [N][GK] bf16
    const float* __restrict__ bias,         // [N]
    unsigned short* __restrict__ Cb, float* __restrict__ Cf,
    int M, int N) {
  extern __shared__ __align__(16) char lds[];

  // ---- locality-aware XCD banding (ntm == 64 assumed) ----
  const int bid = blockIdx.x;
  const int xcd = bid & 7;
  const int i6 = bid >> 3;              // [0, nwg/8)
  const int tm = xcd * 8 + (i6 & 7);    // exclusive 8-row A-band per XCD
  const int tn = i6 >> 3;               // tn walked in lockstep across XCDs

  const int tid = threadIdx.x;
  const int wave = tid >> 6, lane = tid & 63;
  const int wr = wave >> 2, wc = wave & 3;   // 2M x 4N waves, 128x64 out each

  // ---- staging addressing (per-thread, bytes) ----
  const int colb = ((tid & 3) << 4) ^ (((tid >> 3) & 3) << 4);
  const size_t g0 = (size_t)(tid >> 2) * (GK * 2) + colb;
  const size_t g1 = g0 + (size_t)128 * (GK * 2);
  const char* Ab = (const char*)A + (size_t)tm * 256 * (GK * 2);
  const char* Bb = (const char*)Bt + (size_t)tn * 256 * (GK * 2);

#define STAGE(J, DST)                                                     \
  do {                                                                    \
    if ((J) < NREG) {                                                     \
      const int _t = (J) >> 2;                                            \
      const char* _s = (((J)&1) ? Bb : Ab) + (size_t)(_t)*128 +           \
                       ((((J) >> 1) & 1) * 64);                           \
      char* _d = lds + (DST) + (wave << 10);                              \
      gld_lds16(_s + g0, _d);                                             \
      gld_lds16(_s + g1, _d + 8192);                                      \
    }                                                                     \
  } while (0)

  // ---- fragment read addressing ----
  const int fr = lane & 15;
  const int fkb = (lane >> 4) << 4;                           // k-offset bytes
  const int lofs = fr * 64 + (fkb ^ (((fr >> 1) & 3) << 4));  // swizzled

  f32x4 acc[8][4];
#pragma unroll
  for (int m = 0; m < 8; m++)
#pragma unroll
    for (int n = 0; n < 4; n++) acc[m][n] = (f32x4){0.f, 0.f, 0.f, 0.f};
  bf16x8 aA[4], aB[4], b0[4], b1[4];

  // ---- ring cursors: rs[i]=slot(S_{4u+i}); wsl[j]=slot(S_{4u+7+j}) ----
  int rs[4] = {0, SLOT, 2 * SLOT, 3 * SLOT};
  int wsl[4] = {7 * SLOT, 8 * SLOT, 0, SLOT};

  // ---- prologue: stage S_0..S_6 into slots 0..6 ----
  STAGE(0, 0); STAGE(1, SLOT); STAGE(2, 2 * SLOT); STAGE(3, 3 * SLOT);
  STAGE(4, 4 * SLOT); STAGE(5, 5 * SLOT); STAGE(6, 6 * SLOT);
  asm volatile("s_waitcnt vmcnt(6)" ::: "memory");  // S_0..S_3 landed
  __builtin_amdgcn_s_barrier();

  for (int u = 0; u < NKT; ++u) {
    // ---- top: prefetch stages + fragment burst ----
    STAGE(u * 4 + 7, wsl[0]);
    STAGE(u * 4 + 8, wsl[1]);
    {
      const char* a0p = lds + rs[0] + wr * 8192 + lofs;
      const char* b0p = lds + rs[1] + wc * 4096 + lofs;
      const char* b1p = lds + rs[3] + wc * 4096 + lofs;
#pragma unroll
      for (int m = 0; m < 4; m++) aA[m] = *(const bf16x8*)(a0p + m * 1024);
#pragma unroll
      for (int n = 0; n < 4; n++) b0[n] = *(const bf16x8*)(b0p + n * 1024);
#pragma unroll
      for (int m = 0; m < 4; m++) aB[m] = *(const bf16x8*)(a0p + 4096 + m * 1024);
#pragma unroll
      for (int n = 0; n < 4; n++) b1[n] = *(const bf16x8*)(b1p + n * 1024);
    }
    __builtin_amdgcn_sched_barrier(0);  // pin burst above MFMA

    // ---- p0/p1: kstep0 (compiler inserts counted lgkmcnt) ----
    __builtin_amdgcn_s_setprio(1);
#pragma unroll
    for (int m = 0; m < 4; m++)
#pragma unroll
      for (int n = 0; n < 4; n++)
        acc[m][n] = __builtin_amdgcn_mfma_f32_16x16x32_bf16(aA[m], b0[n],
                                                            acc[m][n], 0, 0, 0);
#pragma unroll
    for (int m = 0; m < 4; m++)
#pragma unroll
      for (int n = 0; n < 4; n++)
        acc[4 + m][n] = __builtin_amdgcn_mfma_f32_16x16x32_bf16(
            aB[m], b0[n], acc[4 + m][n], 0, 0, 0);
    __builtin_amdgcn_s_setprio(0);

    // ---- A(k1) reads: overlap with p0/p1 issue above (in-flight) ----
    {
      const char* a1p = lds + rs[2] + wr * 8192 + lofs;
#pragma unroll
      for (int m = 0; m < 4; m++) aA[m] = *(const bf16x8*)(a1p + m * 1024);
#pragma unroll
      for (int m = 0; m < 4; m++) aB[m] = *(const bf16x8*)(a1p + 4096 + m * 1024);
    }
    // ---- mid barrier: WAR gate for S_{4u+9},S_{4u+10} overwrites ----
    asm volatile("s_waitcnt lgkmcnt(12)" ::: "memory");  // reads 1-12 done
    __builtin_amdgcn_s_barrier();
    STAGE(u * 4 + 9, wsl[2]);
    STAGE(u * 4 + 10, wsl[3]);
    __builtin_amdgcn_sched_barrier(0);  // pin stage issue before p2/p3

    // ---- p2/p3: kstep1 ----
    __builtin_amdgcn_s_setprio(1);
#pragma unroll
    for (int m = 0; m < 4; m++)
#pragma unroll
      for (int n = 0; n < 4; n++)
        acc[m][n] = __builtin_amdgcn_mfma_f32_16x16x32_bf16(aA[m], b1[n],
                                                            acc[m][n], 0, 0, 0);
#pragma unroll
    for (int m = 0; m < 4; m++)
#pragma unroll
      for (int n = 0; n < 4; n++)
        acc[4 + m][n] = __builtin_amdgcn_mfma_f32_16x16x32_bf16(
            aB[m], b1[n], acc[4 + m][n], 0, 0, 0);
    __builtin_amdgcn_s_setprio(0);

    asm volatile("s_waitcnt vmcnt(6)" ::: "memory");  // next tile landed
    __builtin_amdgcn_s_barrier();

#pragma unroll
    for (int i = 0; i < 4; i++) {
      rs[i] += 4 * SLOT;  if (rs[i] >= RING)  rs[i] -= RING;
      wsl[i] += 4 * SLOT; if (wsl[i] >= RING) wsl[i] -= RING;
    }
  }
#undef STAGE

  // ---- epilogue: C/D layout col=lane&15, row=(lane>>4)*4+reg ----
  const int fq = lane >> 4;
#pragma unroll
  for (int mp = 0; mp < 8; mp++) {
#pragma unroll
    for (int n = 0; n < 4; n++) {
      const int col = tn * 256 + wc * 64 + n * 16 + fr;
      const float bb = bias[col];
#pragma unroll
      for (int r = 0; r < 4; r++) {
        const int row = tm * 256 + wr * 128 + mp * 16 + fq * 4 + r;
        const float v = acc[mp][n][r] + bb;
        if constexpr (F32OUT) Cf[(size_t)row * N + col] = v;
        else                  Cb[(size_t)row * N + col] = f2bf(v);
      }
    }
  }
}

// ===========================================================================
// MFMA per-token head-attention (v4, passing r7). 1 wave/token, NO LDS.
// ===========================================================================
__global__ __launch_bounds__(256) void attn_mfma(
    const unsigned short* __restrict__ qkv,  // [MTOK][6144] bf16
    unsigned short* __restrict__ attn,       // [MTOK][2048] bf16
    const float* __restrict__ c_scale) {
  const int wave = threadIdx.x >> 6, lane = threadIdx.x & 63;
  const int tok = blockIdx.x * 4 + wave;
  const unsigned short* src = qkv + (size_t)tok * NQKV;
  const int fr = lane & 15;
  const int hi = lane >> 4;

  // ---- Q,K fragments straight from global (identical addressing) ----
  const int fk = hi * 8;
  bf16x8 qf[4], kf[4];
#pragma unroll
  for (int kc = 0; kc < 4; kc++) {
    qf[kc] = *(const bf16x8*)(src + fr * 128 + kc * 32 + fk);
    kf[kc] = *(const bf16x8*)(src + HID + fr * 128 + kc * 32 + fk);
  }

  // ---- S^T = K . Q^T : lane holds S[g=hi*4+r][h=fr] ----
  f32x4 s = (f32x4){0.f, 0.f, 0.f, 0.f};
#pragma unroll
  for (int kc = 0; kc < 4; kc++)
    s = __builtin_amdgcn_mfma_f32_16x16x32_bf16(kf[kc], qf[kc], s, 0, 0, 0);

  const float scale = c_scale[0] * 0.08838834764831845f;  // 1/sqrt(128)
  float pa[4];
#pragma unroll
  for (int r = 0; r < 4; r++) pa[r] = s[r] * scale;

  // ---- softmax over g (rows): in-lane 4 + cross lane-group 16,32 ----
  float mx = fmaxf(fmaxf(pa[0], pa[1]), fmaxf(pa[2], pa[3]));
  mx = fmaxf(mx, __shfl_xor(mx, 16));
  mx = fmaxf(mx, __shfl_xor(mx, 32));
#pragma unroll
  for (int r = 0; r < 4; r++) pa[r] = __expf(pa[r] - mx);
  float sum = pa[0] + pa[1] + pa[2] + pa[3];
  sum += __shfl_xor(sum, 16);
  sum += __shfl_xor(sum, 32);
  float rsum = 1.0f / sum;
#pragma unroll
  for (int r = 0; r < 4; r++) pa[r] *= rsum;

  // ---- P A-frag: slot (hi,j) holds P[h=fr][g=hi*8+j], zero for g>=16.
  //      Source lane for P[fr][g'] is (g'>>2)*16 + fr, register g'&3. ----
  union { bf16x8 v; unsigned short u[8]; uint32_t w[4]; } pf;
  const int sidx0 = fr + (hi * 2) * 16;
#pragma unroll
  for (int j = 0; j < 8; j++) {
    float pv_ = __shfl(pa[j & 3], sidx0 + (j >> 2) * 16);
    pf.u[j] = f2bf(pv_);
  }
  if (lane >= 32) { pf.w[0] = 0; pf.w[1] = 0; pf.w[2] = 0; pf.w[3] = 0; }

  // ---- PV: V-frag slot (hi,j) = V[(hi&1)*8+j][d=dc*16+fr] via scalar
  //      global loads (same kappa_as as P for hi<2; hi>=2 x P=0 = 0). ----
  const unsigned short* vrow = src + 2 * HID + (hi & 1) * 8 * 128 + fr;
  unsigned short* dst = attn + (size_t)tok * HID;
#pragma unroll
  for (int dc = 0; dc < 8; dc++) {
    union { bf16x8 v; unsigned short u[8]; } vf;
#pragma unroll
    for (int j = 0; j < 8; j++) vf.u[j] = vrow[j * 128 + dc * 16];
    f32x4 o = __builtin_amdgcn_mfma_f32_16x16x32_bf16(
        pf.v, vf.v, (f32x4){0.f, 0.f, 0.f, 0.f}, 0, 0, 0);
#pragma unroll
    for (int r = 0; r < 4; r++)
      dst[(hi * 4 + r) * 128 + dc * 16 + fr] = f2bf(o[r]);
  }
}

// ---------------------------------------------------------------------------
extern "C" void kernel_launch(void* const* d_in, const int* in_sizes, int n_in,
                              void* d_out, int out_size, void* d_ws,
                              size_t ws_size, hipStream_t stream) {
  const float* x  = (const float*)d_in[0];
  const float* Wq = (const float*)d_in[1];
  const float* bq = (const float*)d_in[2];
  const float* Wk = (const float*)d_in[3];
  const float* bk = (const float*)d_in[4];
  const float* Wv = (const float*)d_in[5];
  const float* bv = (const float*)d_in[6];
  const float* Wo = (const float*)d_in[7];
  const float* bo = (const float*)d_in[8];
  const float* c_scale = (const float*)d_in[9];
  float* out = (float*)d_out;

  char* ws = (char*)d_ws;
  unsigned short* xb    = (unsigned short*)ws; ws += (size_t)MTOK * HID * 2;
  unsigned short* Wqkvt = (unsigned short*)ws; ws += (size_t)NQKV * HID * 2;
  unsigned short* Wot   = (unsigned short*)ws; ws += (size_t)HID * HID * 2;
  float*          biasq = (float*)ws;          ws += (size_t)NQKV * 4;
  unsigned short* qkv   = (unsigned short*)ws; ws += (size_t)MTOK * NQKV * 2;
  unsigned short* attn  = (unsigned short*)ws; ws += (size_t)MTOK * HID * 2;

  (void)hipFuncSetAttribute((const void*)&gemm256<false>,
                            hipFuncAttributeMaxDynamicSharedMemorySize, RING);
  (void)hipFuncSetAttribute((const void*)&gemm256<true>,
                            hipFuncAttributeMaxDynamicSharedMemorySize, RING);

  convert_f32_bf16<<<2048, 256, 0, stream>>>(x, xb, MTOK * HID / 8);
  transpose4_to_bf16<<<dim3(32, 32, 4), 256, 0, stream>>>(Wq, Wk, Wv, Wo,
                                                          Wqkvt, Wot);
  concat_bias<<<24, 256, 0, stream>>>(bq, bk, bv, biasq);

  // QKV projection: [16384][2048] x [6144][2048]^T -> bf16 [16384][6144]
  gemm256<false><<<(MTOK / 256) * (NQKV / 256), 512, RING, stream>>>(
      xb, Wqkvt, biasq, qkv, nullptr, MTOK, NQKV);
  attn_mfma<<<MTOK / 4, 256, 0, stream>>>(qkv, attn, c_scale);
  // O projection: [16384][2048] x [2048][2048]^T -> f32 out
  gemm256<true><<<(MTOK / 256) * (HID / 256), 512, RING, stream>>>(
      attn, Wot, bo, nullptr, out, MTOK, HID);
}

// Round 13
// 613.755 us; speedup vs baseline: 1.0512x; 1.0016x over previous
//
#include <hip/hip_runtime.h>
#include <hip/hip_bf16.h>
#include <stdint.h>

// Problem constants
#define MTOK 16384   // B*S
#define HID  2048
#define NQKV 6144    // 3*HID
#define GK   2048    // K of both GEMMs
#define NKT  (GK / 64)    // 32 K-tiles
#define NREG (NKT * 4)    // 128 staging regions (A_k0,B_k0,A_k1,B_k1 per tile)
#define SLOT 16384        // bytes per LDS region slot
#define RING (9 * SLOT)   // 147456 B: 9-slot ring

typedef __attribute__((ext_vector_type(8))) short bf16x8;
typedef __attribute__((ext_vector_type(4))) float f32x4;

__device__ __forceinline__ unsigned short f2bf(float f) {
  uint32_t u = __float_as_uint(f);
  u = (u + 0x7FFFu + ((u >> 16) & 1u)) >> 16;   // round-to-nearest-even
  return (unsigned short)u;
}
__device__ __forceinline__ void bf2x2(uint32_t u, float& lo, float& hi) {
  lo = __uint_as_float(u << 16);
  hi = __uint_as_float(u & 0xFFFF0000u);
}

__device__ __forceinline__ void gld_lds16(const void* g, void* l) {
  __builtin_amdgcn_global_load_lds(
      (const __attribute__((address_space(1))) uint32_t*)g,
      (__attribute__((address_space(3))) uint32_t*)l, 16, 0, 0);
}

// ---------------- fp32 -> bf16 elementwise convert (8 elems/thread/iter) ---
__global__ void convert_f32_bf16(const float* __restrict__ in,
                                 unsigned short* __restrict__ out, int n8) {
  int idx = blockIdx.x * blockDim.x + threadIdx.x;
  int stride = gridDim.x * blockDim.x;
  for (int i = idx; i < n8; i += stride) {
    const float4* p = (const float4*)(in + (size_t)i * 8);
    float4 a = p[0], b = p[1];
    union { bf16x8 v; unsigned short u[8]; } o;
    o.u[0] = f2bf(a.x); o.u[1] = f2bf(a.y); o.u[2] = f2bf(a.z); o.u[3] = f2bf(a.w);
    o.u[4] = f2bf(b.x); o.u[5] = f2bf(b.y); o.u[6] = f2bf(b.z); o.u[7] = f2bf(b.w);
    *(bf16x8*)(out + (size_t)i * 8) = o.v;
  }
}

// ------- 4x W[K][N] f32 -> Wt[N][K] bf16 (64x64 LDS tiles), z picks W ------
__global__ void transpose4_to_bf16(const float* __restrict__ Wq,
                                   const float* __restrict__ Wk,
                                   const float* __restrict__ Wv,
                                   const float* __restrict__ Wo,
                                   unsigned short* __restrict__ Wqkvt,
                                   unsigned short* __restrict__ Wot) {
  __shared__ float tile[64][65];
  const float* W;
  unsigned short* Wt;
  const int z = blockIdx.z;
  if (z == 0)      { W = Wq; Wt = Wqkvt; }
  else if (z == 1) { W = Wk; Wt = Wqkvt + (size_t)HID * HID; }
  else if (z == 2) { W = Wv; Wt = Wqkvt + (size_t)2 * HID * HID; }
  else             { W = Wo; Wt = Wot; }
  int tk = blockIdx.x * 64, tn = blockIdx.y * 64;
  int t = threadIdx.x;
  int c = t & 63, rb = t >> 6;
#pragma unroll
  for (int i = 0; i < 16; i++) {
    int r = i * 4 + rb;
    tile[r][c] = W[(size_t)(tk + r) * HID + tn + c];
  }
  __syncthreads();
#pragma unroll
  for (int i = 0; i < 16; i++) {
    int r = i * 4 + rb;  // r = n index, c = k index
    Wt[(size_t)(tn + r) * HID + tk + c] = f2bf(tile[c][r]);
  }
}

// ---------------- bias concat [bq|bk|bv] -> [6144] f32 ---------------------
__global__ void concat_bias(const float* __restrict__ bq,
                            const float* __restrict__ bk,
                            const float* __restrict__ bv,
                            float* __restrict__ out) {
  int i = blockIdx.x * blockDim.x + threadIdx.x;
  if (i < 2048)       out[i] = bq[i];
  else if (i < 4096)  out[i] = bk[i - 2048];
  else if (i < 6144)  out[i] = bv[i - 4096];
}

// ===========================================================================
// 256x256 bf16 GEMM, burst-read 2-barrier-per-K-tile schedule (r7 proven,
// byte-identical revert; (512,2) is the replay-validated codegen — FROZEN.
// Module content is also frozen: adding/changing ANY kernel in this TU
// perturbed gemm256 codegen and broke the counted-waitcnt ledger, r10/r12).
//
// GRID MAPPING: XCD x owns an exclusive 8-row A-band (tm = x*8 + i%8),
// walking tn = i/8 across it. A fetched from HBM once chip-wide;
// B working set L2/L3-resident.
//
// LDS: 9-slot ring of 16 KiB regions. Region S_J (J = 4u + {0:A_k0,1:B_k0,
// 2:A_k1,3:B_k1}) in slot J mod 9. Swizzle involution byte ^= ((row>>1)&3)<<4
// on ds_read addr, inverse pre-applied to global_load_lds source (rule #21).
//
// Per K-tile u (ledger-verified):
//   top:  STAGE S_{4u+7},S_{4u+8}; burst 16 ds_reads (A k0 both halves, B k0,
//         B k1); sched_barrier
//   p0/p1 MFMA (counted lgkmcnt by compiler); then 8 ds_reads A(k1)
//   mid:  lgkmcnt(12) + s_barrier; STAGE S_{4u+9},S_{4u+10}
//   p2/p3 MFMA; vmcnt(6); s_barrier (close)
// ===========================================================================
template <bool F32OUT>
__global__ __launch_bounds__(512, 2) void gemm256(
    const unsigned short* __restrict__ A,   // [M][GK] bf16
    const unsigned short* __restrict__ Bt,  // [N][GK] bf16
    const float* __restrict__ bias,         // [N]
    unsigned short* __restrict__ Cb, float* __restrict__ Cf,
    int M, int N) {
  extern __shared__ __align__(16) char lds[];

  // ---- locality-aware XCD banding (ntm == 64 assumed) ----
  const int bid = blockIdx.x;
  const int xcd = bid & 7;
  const int i6 = bid >> 3;              // [0, nwg/8)
  const int tm = xcd * 8 + (i6 & 7);    // exclusive 8-row A-band per XCD
  const int tn = i6 >> 3;               // tn walked in lockstep across XCDs

  const int tid = threadIdx.x;
  const int wave = tid >> 6, lane = tid & 63;
  const int wr = wave >> 2, wc = wave & 3;   // 2M x 4N waves, 128x64 out each

  // ---- staging addressing (per-thread, bytes) ----
  const int colb = ((tid & 3) << 4) ^ (((tid >> 3) & 3) << 4);
  const size_t g0 = (size_t)(tid >> 2) * (GK * 2) + colb;
  const size_t g1 = g0 + (size_t)128 * (GK * 2);
  const char* Ab = (const char*)A + (size_t)tm * 256 * (GK * 2);
  const char* Bb = (const char*)Bt + (size_t)tn * 256 * (GK * 2);

#define STAGE(J, DST)                                                     \
  do {                                                                    \
    if ((J) < NREG) {                                                     \
      const int _t = (J) >> 2;                                            \
      const char* _s = (((J)&1) ? Bb : Ab) + (size_t)(_t)*128 +           \
                       ((((J) >> 1) & 1) * 64);                           \
      char* _d = lds + (DST) + (wave << 10);                              \
      gld_lds16(_s + g0, _d);                                             \
      gld_lds16(_s + g1, _d + 8192);                                      \
    }                                                                     \
  } while (0)

  // ---- fragment read addressing ----
  const int fr = lane & 15;
  const int fkb = (lane >> 4) << 4;                           // k-offset bytes
  const int lofs = fr * 64 + (fkb ^ (((fr >> 1) & 3) << 4));  // swizzled

  f32x4 acc[8][4];
#pragma unroll
  for (int m = 0; m < 8; m++)
#pragma unroll
    for (int n = 0; n < 4; n++) acc[m][n] = (f32x4){0.f, 0.f, 0.f, 0.f};
  bf16x8 aA[4], aB[4], b0[4], b1[4];

  // ---- ring cursors: rs[i]=slot(S_{4u+i}); wsl[j]=slot(S_{4u+7+j}) ----
  int rs[4] = {0, SLOT, 2 * SLOT, 3 * SLOT};
  int wsl[4] = {7 * SLOT, 8 * SLOT, 0, SLOT};

  // ---- prologue: stage S_0..S_6 into slots 0..6 ----
  STAGE(0, 0); STAGE(1, SLOT); STAGE(2, 2 * SLOT); STAGE(3, 3 * SLOT);
  STAGE(4, 4 * SLOT); STAGE(5, 5 * SLOT); STAGE(6, 6 * SLOT);
  asm volatile("s_waitcnt vmcnt(6)" ::: "memory");  // S_0..S_3 landed
  __builtin_amdgcn_s_barrier();

  for (int u = 0; u < NKT; ++u) {
    // ---- top: prefetch stages + fragment burst ----
    STAGE(u * 4 + 7, wsl[0]);
    STAGE(u * 4 + 8, wsl[1]);
    {
      const char* a0p = lds + rs[0] + wr * 8192 + lofs;
      const char* b0p = lds + rs[1] + wc * 4096 + lofs;
      const char* b1p = lds + rs[3] + wc * 4096 + lofs;
#pragma unroll
      for (int m = 0; m < 4; m++) aA[m] = *(const bf16x8*)(a0p + m * 1024);
#pragma unroll
      for (int n = 0; n < 4; n++) b0[n] = *(const bf16x8*)(b0p + n * 1024);
#pragma unroll
      for (int m = 0; m < 4; m++) aB[m] = *(const bf16x8*)(a0p + 4096 + m * 1024);
#pragma unroll
      for (int n = 0; n < 4; n++) b1[n] = *(const bf16x8*)(b1p + n * 1024);
    }
    __builtin_amdgcn_sched_barrier(0);  // pin burst above MFMA

    // ---- p0/p1: kstep0 (compiler inserts counted lgkmcnt) ----
    __builtin_amdgcn_s_setprio(1);
#pragma unroll
    for (int m = 0; m < 4; m++)
#pragma unroll
      for (int n = 0; n < 4; n++)
        acc[m][n] = __builtin_amdgcn_mfma_f32_16x16x32_bf16(aA[m], b0[n],
                                                            acc[m][n], 0, 0, 0);
#pragma unroll
    for (int m = 0; m < 4; m++)
#pragma unroll
      for (int n = 0; n < 4; n++)
        acc[4 + m][n] = __builtin_amdgcn_mfma_f32_16x16x32_bf16(
            aB[m], b0[n], acc[4 + m][n], 0, 0, 0);
    __builtin_amdgcn_s_setprio(0);

    // ---- A(k1) reads: overlap with p0/p1 issue above (in-flight) ----
    {
      const char* a1p = lds + rs[2] + wr * 8192 + lofs;
#pragma unroll
      for (int m = 0; m < 4; m++) aA[m] = *(const bf16x8*)(a1p + m * 1024);
#pragma unroll
      for (int m = 0; m < 4; m++) aB[m] = *(const bf16x8*)(a1p + 4096 + m * 1024);
    }
    // ---- mid barrier: WAR gate for S_{4u+9},S_{4u+10} overwrites ----
    asm volatile("s_waitcnt lgkmcnt(12)" ::: "memory");  // reads 1-12 done
    __builtin_amdgcn_s_barrier();
    STAGE(u * 4 + 9, wsl[2]);
    STAGE(u * 4 + 10, wsl[3]);
    __builtin_amdgcn_sched_barrier(0);  // pin stage issue before p2/p3

    // ---- p2/p3: kstep1 ----
    __builtin_amdgcn_s_setprio(1);
#pragma unroll
    for (int m = 0; m < 4; m++)
#pragma unroll
      for (int n = 0; n < 4; n++)
        acc[m][n] = __builtin_amdgcn_mfma_f32_16x16x32_bf16(aA[m], b1[n],
                                                            acc[m][n], 0, 0, 0);
#pragma unroll
    for (int m = 0; m < 4; m++)
#pragma unroll
      for (int n = 0; n < 4; n++)
        acc[4 + m][n] = __builtin_amdgcn_mfma_f32_16x16x32_bf16(
            aB[m], b1[n], acc[4 + m][n], 0, 0, 0);
    __builtin_amdgcn_s_setprio(0);

    asm volatile("s_waitcnt vmcnt(6)" ::: "memory");  // next tile landed
    __builtin_amdgcn_s_barrier();

#pragma unroll
    for (int i = 0; i < 4; i++) {
      rs[i] += 4 * SLOT;  if (rs[i] >= RING)  rs[i] -= RING;
      wsl[i] += 4 * SLOT; if (wsl[i] >= RING) wsl[i] -= RING;
    }
  }
#undef STAGE

  // ---- epilogue: C/D layout col=lane&15, row=(lane>>4)*4+reg ----
  const int fq = lane >> 4;
#pragma unroll
  for (int mp = 0; mp < 8; mp++) {
#pragma unroll
    for (int n = 0; n < 4; n++) {
      const int col = tn * 256 + wc * 64 + n * 16 + fr;
      const float bb = bias[col];
#pragma unroll
      for (int r = 0; r < 4; r++) {
        const int row = tm * 256 + wr * 128 + mp * 16 + fq * 4 + r;
        const float v = acc[mp][n][r] + bb;
        if constexpr (F32OUT) Cf[(size_t)row * N + col] = v;
        else                  Cb[(size_t)row * N + col] = f2bf(v);
      }
    }
  }
}

// ===========================================================================
// MFMA per-token head-attention (v4, passing r7). 1 wave/token, NO LDS.
// ===========================================================================
__global__ __launch_bounds__(256) void attn_mfma(
    const unsigned short* __restrict__ qkv,  // [MTOK][6144] bf16
    unsigned short* __restrict__ attn,       // [MTOK][2048] bf16
    const float* __restrict__ c_scale) {
  const int wave = threadIdx.x >> 6, lane = threadIdx.x & 63;
  const int tok = blockIdx.x * 4 + wave;
  const unsigned short* src = qkv + (size_t)tok * NQKV;
  const int fr = lane & 15;
  const int hi = lane >> 4;

  // ---- Q,K fragments straight from global (identical addressing) ----
  const int fk = hi * 8;
  bf16x8 qf[4], kf[4];
#pragma unroll
  for (int kc = 0; kc < 4; kc++) {
    qf[kc] = *(const bf16x8*)(src + fr * 128 + kc * 32 + fk);
    kf[kc] = *(const bf16x8*)(src + HID + fr * 128 + kc * 32 + fk);
  }

  // ---- S^T = K . Q^T : lane holds S[g=hi*4+r][h=fr] ----
  f32x4 s = (f32x4){0.f, 0.f, 0.f, 0.f};
#pragma unroll
  for (int kc = 0; kc < 4; kc++)
    s = __builtin_amdgcn_mfma_f32_16x16x32_bf16(kf[kc], qf[kc], s, 0, 0, 0);

  const float scale = c_scale[0] * 0.08838834764831845f;  // 1/sqrt(128)
  float pa[4];
#pragma unroll
  for (int r = 0; r < 4; r++) pa[r] = s[r] * scale;

  // ---- softmax over g (rows): in-lane 4 + cross lane-group 16,32 ----
  float mx = fmaxf(fmaxf(pa[0], pa[1]), fmaxf(pa[2], pa[3]));
  mx = fmaxf(mx, __shfl_xor(mx, 16));
  mx = fmaxf(mx, __shfl_xor(mx, 32));
#pragma unroll
  for (int r = 0; r < 4; r++) pa[r] = __expf(pa[r] - mx);
  float sum = pa[0] + pa[1] + pa[2] + pa[3];
  sum += __shfl_xor(sum, 16);
  sum += __shfl_xor(sum, 32);
  float rsum = 1.0f / sum;
#pragma unroll
  for (int r = 0; r < 4; r++) pa[r] *= rsum;

  // ---- P A-frag: slot (hi,j) holds P[h=fr][g=hi*8+j], zero for g>=16.
  //      Source lane for P[fr][g'] is (g'>>2)*16 + fr, register g'&3. ----
  union { bf16x8 v; unsigned short u[8]; uint32_t w[4]; } pf;
  const int sidx0 = fr + (hi * 2) * 16;
#pragma unroll
  for (int j = 0; j < 8; j++) {
    float pv_ = __shfl(pa[j & 3], sidx0 + (j >> 2) * 16);
    pf.u[j] = f2bf(pv_);
  }
  if (lane >= 32) { pf.w[0] = 0; pf.w[1] = 0; pf.w[2] = 0; pf.w[3] = 0; }

  // ---- PV: V-frag slot (hi,j) = V[(hi&1)*8+j][d=dc*16+fr] via scalar
  //      global loads (same kappa_as as P for hi<2; hi>=2 x P=0 = 0). ----
  const unsigned short* vrow = src + 2 * HID + (hi & 1) * 8 * 128 + fr;
  unsigned short* dst = attn + (size_t)tok * HID;
#pragma unroll
  for (int dc = 0; dc < 8; dc++) {
    union { bf16x8 v; unsigned short u[8]; } vf;
#pragma unroll
    for (int j = 0; j < 8; j++) vf.u[j] = vrow[j * 128 + dc * 16];
    f32x4 o = __builtin_amdgcn_mfma_f32_16x16x32_bf16(
        pf.v, vf.v, (f32x4){0.f, 0.f, 0.f, 0.f}, 0, 0, 0);
#pragma unroll
    for (int r = 0; r < 4; r++)
      dst[(hi * 4 + r) * 128 + dc * 16 + fr] = f2bf(o[r]);
  }
}

// ---------------------------------------------------------------------------
extern "C" void kernel_launch(void* const* d_in, const int* in_sizes, int n_in,
                              void* d_out, int out_size, void* d_ws,
                              size_t ws_size, hipStream_t stream) {
  const float* x  = (const float*)d_in[0];
  const float* Wq = (const float*)d_in[1];
  const float* bq = (const float*)d_in[2];
  const float* Wk = (const float*)d_in[3];
  const float* bk = (const float*)d_in[4];
  const float* Wv = (const float*)d_in[5];
  const float* bv = (const float*)d_in[6];
  const float* Wo = (const float*)d_in[7];
  const float* bo = (const float*)d_in[8];
  const float* c_scale = (const float*)d_in[9];
  float* out = (float*)d_out;

  char* ws = (char*)d_ws;
  unsigned short* xb    = (unsigned short*)ws; ws += (size_t)MTOK * HID * 2;
  unsigned short* Wqkvt = (unsigned short*)ws; ws += (size_t)NQKV * HID * 2;
  unsigned short* Wot   = (unsigned short*)ws; ws += (size_t)HID * HID * 2;
  float*          biasq = (float*)ws;          ws += (size_t)NQKV * 4;
  unsigned short* qkv   = (unsigned short*)ws; ws += (size_t)MTOK * NQKV * 2;
  unsigned short* attn  = (unsigned short*)ws; ws += (size_t)MTOK * HID * 2;

  (void)hipFuncSetAttribute((const void*)&gemm256<false>,
                            hipFuncAttributeMaxDynamicSharedMemorySize, RING);
  (void)hipFuncSetAttribute((const void*)&gemm256<true>,
                            hipFuncAttributeMaxDynamicSharedMemorySize, RING);

  convert_f32_bf16<<<2048, 256, 0, stream>>>(x, xb, MTOK * HID / 8);
  transpose4_to_bf16<<<dim3(32, 32, 4), 256, 0, stream>>>(Wq, Wk, Wv, Wo,
                                                          Wqkvt, Wot);
  concat_bias<<<24, 256, 0, stream>>>(bq, bk, bv, biasq);

  // QKV projection: [16384][2048] x [6144][2048]^T -> bf16 [16384][6144]
  gemm256<false><<<(MTOK / 256) * (NQKV / 256), 512, RING, stream>>>(
      xb, Wqkvt, biasq, qkv, nullptr, MTOK, NQKV);
  attn_mfma<<<MTOK / 4, 256, 0, stream>>>(qkv, attn, c_scale);
  // O projection: [16384][2048] x [2048][2048]^T -> f32 out
  gemm256<true><<<(MTOK / 256) * (HID / 256), 512, RING, stream>>>(
      attn, Wot, bo, nullptr, out, MTOK, HID);
}